// Round 2
// baseline (381.241 us; speedup 1.0000x reference)
//
#include <hip/hip_runtime.h>
#include <stdint.h>
#include <stddef.h>

// Problem constants
#define HB 8
#define HN 1024
#define HC 768
#define HH 12
#define HD 64
#define ROWS (HB*HN)      // 8192
#define BH (HB*HH)        // 96

using s16x4  = __attribute__((ext_vector_type(4))) short;
using bf16x8 = __attribute__((ext_vector_type(8))) short;
using f32x4  = __attribute__((ext_vector_type(4))) float;

__device__ __forceinline__ short f2bf(float f) {
  union { float f; uint32_t u; } c; c.f = f;
  uint32_t u = c.u;
  uint32_t r = (u + 0x7fffu + ((u >> 16) & 1u)) >> 16;   // RNE
  return (short)r;
}
__device__ __forceinline__ float bf2f(short s) {
  union { uint32_t u; float f; } c; c.u = ((uint32_t)(uint16_t)s) << 16;
  return c.f;
}
// pack two f32 -> {bf16(a) | bf16(b)<<16} with RNE, via v_perm_b32
__device__ __forceinline__ uint32_t pack_bf16_rne(float a, float b) {
  union { float f; uint32_t u; } ca, cb; ca.f = a; cb.f = b;
  uint32_t ra = ca.u + 0x7fffu + ((ca.u >> 16) & 1u);
  uint32_t rb = cb.u + 0x7fffu + ((cb.u >> 16) & 1u);
  return __builtin_amdgcn_perm(rb, ra, 0x07060302);  // {rb[31:16], ra[31:16]}
}
__device__ __forceinline__ f32x4 mfma16(bf16x8 a, bf16x8 b, f32x4 c) {
  return __builtin_amdgcn_mfma_f32_16x16x32_bf16(a, b, c, 0, 0, 0);
}
// async global->LDS, 16B per lane. LDS dest MUST be wave-uniform base + lane*16.
__device__ __forceinline__ void gll16(const void* g, void* l) {
  __builtin_amdgcn_global_load_lds((const __attribute__((address_space(1))) void*)g,
                                   (__attribute__((address_space(3))) void*)l,
                                   16, 0, 0);
}

// ---------------- f32 -> bf16 convert (vectorized x4) ----------------
__global__ void cvt_kernel(const float* __restrict__ in, short* __restrict__ out, int n4) {
  int i = blockIdx.x * 256 + threadIdx.x;
  if (i >= n4) return;
  float4 v = ((const float4*)in)[i];
  s16x4 o;
  o.x = f2bf(v.x); o.y = f2bf(v.y); o.z = f2bf(v.z); o.w = f2bf(v.w);
  ((s16x4*)out)[i] = o;
}

// ---------------- GEMM: C[M,N] = A[M,K] * B[N,K]^T  (bf16 in, OutT out) ------
// m97 recipe: 128x128 tile, BK=64, 256 threads = 4 waves (2x2), each wave 64x64
// = 4x4 tiles of 16x16x32 MFMA. global_load_lds width 16 staging.
__device__ __forceinline__ void store_c(float* p, float v) { *p = v; }
__device__ __forceinline__ void store_c(short* p, float v) { *p = f2bf(v); }

template <typename OutT>
__global__ __launch_bounds__(256) void gemm_bt(const short* __restrict__ A,
                                               const short* __restrict__ Bw,
                                               OutT* __restrict__ C,
                                               int M, int N, int K) {
  __shared__ short As[128*64];
  __shared__ short Bs[128*64];
  const int m0 = blockIdx.y * 128, n0 = blockIdx.x * 128;
  const int tid = threadIdx.x;
  const int lane = tid & 63, w = tid >> 6, quad = lane >> 4, lc = lane & 15;
  const int wr = w >> 1, wc = w & 1;
  f32x4 acc[4][4] = {};
  for (int kt = 0; kt < K; kt += 64) {
#pragma unroll
    for (int i = 0; i < 4; ++i) {
      const int chunk = i*256 + tid;          // 1024 chunks of 8 elems = 128x64
      const int r = chunk >> 3, cb = chunk & 7;
      gll16(A  + (size_t)(m0 + r)*K + kt + cb*8, (void*)(As + (size_t)chunk*8));
      gll16(Bw + (size_t)(n0 + r)*K + kt + cb*8, (void*)(Bs + (size_t)chunk*8));
    }
    __syncthreads();
#pragma unroll
    for (int kk = 0; kk < 2; ++kk) {
      bf16x8 af[4], bfr[4];
#pragma unroll
      for (int mt = 0; mt < 4; ++mt)
        af[mt] = *(const bf16x8*)(As + (wr*64 + mt*16 + lc)*64 + kk*32 + quad*8);
#pragma unroll
      for (int nt = 0; nt < 4; ++nt)
        bfr[nt] = *(const bf16x8*)(Bs + (wc*64 + nt*16 + lc)*64 + kk*32 + quad*8);
#pragma unroll
      for (int mt = 0; mt < 4; ++mt)
#pragma unroll
        for (int nt = 0; nt < 4; ++nt)
          acc[mt][nt] = mfma16(af[mt], bfr[nt], acc[mt][nt]);
    }
    __syncthreads();
  }
  // epilogue: C/D layout col=lane&15, row=quad*4+reg  (m89/m91 verified)
#pragma unroll
  for (int mt = 0; mt < 4; ++mt)
#pragma unroll
    for (int nt = 0; nt < 4; ++nt)
#pragma unroll
      for (int r = 0; r < 4; ++r) {
        const int row = m0 + wr*64 + mt*16 + quad*4 + r;
        const int col = n0 + wc*64 + nt*16 + lc;
        store_c(C + (size_t)row*N + col, acc[mt][nt][r]);
      }
}

// ---------------- per-head LayerNorm(q,k) + V transpose ----------------
// qkvb: bf16 [8192][2304], col = t*768 + h*64 + d
// Qb,Kb: bf16 [BH][1024][64]   (q scaled by 1/8)
// Vtb  : bf16 [BH][64][1024]   transposed AND key-permuted within 32-groups:
//   storage col for key n = (n & ~31) | ((n & 15) << 1) | ((n >> 4) & 1)
//   (matches the packed-pair P stash in attn_kernel; PV contraction invariant)
__global__ __launch_bounds__(256) void ln_qkv_kernel(const short* __restrict__ qkvb,
                                                     short* __restrict__ Qb,
                                                     short* __restrict__ Kb,
                                                     short* __restrict__ Vtb) {
  const int blk = blockIdx.x;            // (bh)*16 + tile
  const int tile = blk & 15, bh = blk >> 4;
  const int b = bh / HH, h = bh % HH;
  const int n0 = tile * 64;
  const int tid = threadIdx.x, w = tid >> 6, lane = tid & 63;

  // q (t=0, scaled) and k (t=1): one row per wave pass, lane=d
#pragma unroll
  for (int t = 0; t < 2; ++t) {
    const int colbase = t*HC + h*HD;
    short* outp = (t == 0) ? Qb : Kb;
    for (int i = 0; i < 16; ++i) {
      const int n = n0 + w*16 + i;
      const float v = bf2f(qkvb[(size_t)(b*HN + n)*(3*HC) + colbase + lane]);
      float s = v;
#pragma unroll
      for (int off = 1; off < 64; off <<= 1) s += __shfl_xor(s, off);
      const float mean = s * (1.0f/64.0f);
      const float d = v - mean;
      float s2 = d*d;
#pragma unroll
      for (int off = 1; off < 64; off <<= 1) s2 += __shfl_xor(s2, off);
      const float inv = rsqrtf(s2 * (1.0f/64.0f) + 1e-5f);
      float o = d * inv;
      if (t == 0) o *= 0.125f;           // SCALE = 64^-0.5
      outp[((size_t)bh*HN + n)*HD + lane] = f2bf(o);
    }
  }
  // v: 64x64 transpose via LDS (pad 65 -> conflict-free)
  __shared__ float vt[64][65];
#pragma unroll
  for (int i = 0; i < 16; ++i) {
    const int idx = i*256 + tid; const int r = idx >> 6, dcol = idx & 63;
    vt[r][dcol] = bf2f(qkvb[(size_t)(b*HN + n0 + r)*(3*HC) + 2*HC + h*HD + dcol]);
  }
  __syncthreads();
#pragma unroll
  for (int i = 0; i < 16; ++i) {
    const int idx = i*256 + tid; const int dd = idx >> 6, nn = idx & 63;
    const int cperm = (nn & ~31) | ((nn & 15) << 1) | ((nn >> 4) & 1);
    Vtb[((size_t)bh*HD + dd)*HN + n0 + cperm] = f2bf(vt[nn][dd]);
  }
}

// ---------------- flash attention (no K/V LDS staging, no barriers) ----------
// 1 block per (bh, 64-row q-tile). 4 waves x 16 q-rows. K/V chunks of 128.
// K/V fragments load straight from global (L1 serves the 4-wave redundancy;
// worst-case L2 traffic ~1.6 GB << 34.5 TB/s * 50us). Only LDS use is the
// wave-private P transpose stash -> zero __syncthreads, 17.4 KB LDS.
__global__ __launch_bounds__(256, 4) void attn_kernel(const short* __restrict__ Qb,
                                                      const short* __restrict__ Kb,
                                                      const short* __restrict__ Vtb,
                                                      short* __restrict__ AOb) {
  const int blk = blockIdx.x;
  const int qt = blk & 15, bh = blk >> 4;
  const int b = bh / HH, h = bh % HH;
  const int tid = threadIdx.x, w = tid >> 6, lane = tid & 63;
  const int quad = lane >> 4, lc = lane & 15;

  __shared__ short Ps[4][16][136];   // per-wave P stash; pitch 136 (b128 reads conflict-free)

  // Q A-fragments: A[m=lane&15][k=quad*8+j] (m120-verified layout)
  const int mrow = qt*64 + w*16 + lc;
  bf16x8 aq[2];
  aq[0] = *(const bf16x8*)(Qb + ((size_t)bh*HN + mrow)*HD + quad*8);
  aq[1] = *(const bf16x8*)(Qb + ((size_t)bh*HN + mrow)*HD + 32 + quad*8);

  const short* kbh = Kb  + (size_t)bh*HN*HD;
  const short* vbh = Vtb + (size_t)bh*HD*HN;

  f32x4 oacc[4] = {};
  float m_i[4], l_i[4];
#pragma unroll
  for (int r = 0; r < 4; ++r) { m_i[r] = -INFINITY; l_i[r] = 0.f; }

  for (int ck = 0; ck < 8; ++ck) {
    const int nc0 = ck*128;

    // S = Q K^T : 16 MFMAs; B-fragments straight from global
    f32x4 sacc[8] = {};
#pragma unroll
    for (int kk = 0; kk < 2; ++kk) {
      bf16x8 bk[8];
#pragma unroll
      for (int nt = 0; nt < 8; ++nt)
        bk[nt] = *(const bf16x8*)(kbh + (size_t)(nc0 + nt*16 + lc)*HD + kk*32 + quad*8);
#pragma unroll
      for (int nt = 0; nt < 8; ++nt)
        sacc[nt] = mfma16(aq[kk], bk[nt], sacc[nt]);
    }

    // online softmax (per row r, reduce over 16 lanes of the quad)
#pragma unroll
    for (int r = 0; r < 4; ++r) {
      float mc = sacc[0][r];
#pragma unroll
      for (int nt = 1; nt < 8; ++nt) mc = fmaxf(mc, sacc[nt][r]);
#pragma unroll
      for (int off = 1; off < 16; off <<= 1) mc = fmaxf(mc, __shfl_xor(mc, off));
      const float mnew = fmaxf(m_i[r], mc);
      const float alpha = __expf(m_i[r] - mnew);
      float lsum = 0.f;
#pragma unroll
      for (int nt = 0; nt < 8; ++nt) {
        const float p = __expf(sacc[nt][r] - mnew);
        sacc[nt][r] = p;
        lsum += p;
      }
#pragma unroll
      for (int off = 1; off < 16; off <<= 1) lsum += __shfl_xor(lsum, off);
      l_i[r] = l_i[r]*alpha + lsum;
      m_i[r] = mnew;
#pragma unroll
      for (int nt2 = 0; nt2 < 4; ++nt2) oacc[nt2][r] *= alpha;
    }

    // P stash, C-layout -> A-layout, packed pairs (key-permuted to match Vtb):
    // u32 col g*16+lc holds keys {g*32+lc, g*32+16+lc} = sacc[2g], sacc[2g+1]
#pragma unroll
    for (int g = 0; g < 4; ++g)
#pragma unroll
      for (int r = 0; r < 4; ++r)
        ((uint32_t*)&Ps[w][quad*4 + r][0])[g*16 + lc] =
            pack_bf16_rne(sacc[2*g][r], sacc[2*g + 1][r]);

    // O += P V : 16 MFMAs; V B-fragments straight from global (permuted layout)
#pragma unroll
    for (int kk = 0; kk < 4; ++kk) {
      bf16x8 ap = *(const bf16x8*)(&Ps[w][lc][kk*32 + quad*8]);
      bf16x8 bv[4];
#pragma unroll
      for (int nt2 = 0; nt2 < 4; ++nt2)
        bv[nt2] = *(const bf16x8*)(vbh + (size_t)(nt2*16 + lc)*HN + nc0 + kk*32 + quad*8);
#pragma unroll
      for (int nt2 = 0; nt2 < 4; ++nt2)
        oacc[nt2] = mfma16(ap, bv[nt2], oacc[nt2]);
    }
  }

  // epilogue: write [b][n][h][d] bf16 (input layout of proj GEMM)
#pragma unroll
  for (int nt2 = 0; nt2 < 4; ++nt2)
#pragma unroll
    for (int r = 0; r < 4; ++r) {
      const int row = qt*64 + w*16 + quad*4 + r;
      const int d   = nt2*16 + lc;
      const float val = oacc[nt2][r] / l_i[r];
      AOb[((size_t)(b*HN + row))*HC + h*HD + d] = f2bf(val);
    }
}

// ---------------- launch ----------------
extern "C" void kernel_launch(void* const* d_in, const int* in_sizes, int n_in,
                              void* d_out, int out_size, void* d_ws, size_t ws_size,
                              hipStream_t stream) {
  const float* x     = (const float*)d_in[0];
  const float* wqkv  = (const float*)d_in[1];
  const float* wproj = (const float*)d_in[2];
  float* out = (float*)d_out;

  char* ws = (char*)d_ws;
  size_t off = 0;
  auto alloc = [&](size_t bytes) -> void* {
    void* p = ws + off; off += (bytes + 255) & ~(size_t)255; return p;
  };
  short* xb     = (short*)alloc((size_t)ROWS*HC*2);        // 12.6 MB
  short* wqkvb  = (short*)alloc((size_t)3*HC*HC*2);        //  3.5 MB
  short* wprojb = (short*)alloc((size_t)HC*HC*2);          //  1.2 MB
  short* qkvb   = (short*)alloc((size_t)ROWS*3*HC*2);      // 37.7 MB
  short* Qb     = (short*)alloc((size_t)BH*HN*HD*2);       // 12.6 MB
  short* Kb     = (short*)alloc((size_t)BH*HN*HD*2);       // 12.6 MB
  short* Vtb    = (short*)alloc((size_t)BH*HD*HN*2);       // 12.6 MB
  short* AOb    = (short*)alloc((size_t)ROWS*HC*2);        // 12.6 MB  (~105 MB total)

  { int n4 = ROWS*HC/4;     cvt_kernel<<<(n4+255)/256, 256, 0, stream>>>(x, xb, n4); }
  { int n4 = 3*HC*HC/4;     cvt_kernel<<<(n4+255)/256, 256, 0, stream>>>(wqkv, wqkvb, n4); }
  { int n4 = HC*HC/4;       cvt_kernel<<<(n4+255)/256, 256, 0, stream>>>(wproj, wprojb, n4); }

  gemm_bt<short><<<dim3(3*HC/128, ROWS/128), 256, 0, stream>>>(xb, wqkvb, qkvb,
                                                               ROWS, 3*HC, HC);
  ln_qkv_kernel<<<BH*16, 256, 0, stream>>>(qkvb, Qb, Kb, Vtb);
  attn_kernel<<<BH*16, 256, 0, stream>>>(Qb, Kb, Vtb, AOb);
  gemm_bt<float><<<dim3(HC/128, ROWS/128), 256, 0, stream>>>(AOb, wprojb, out,
                                                             ROWS, HC, HC);
}

// Round 3
// 265.095 us; speedup vs baseline: 1.4381x; 1.4381x over previous
//
#include <hip/hip_runtime.h>
#include <stdint.h>
#include <stddef.h>

// Problem constants
#define HB 8
#define HN 1024
#define HC 768
#define HH 12
#define HD 64
#define ROWS (HB*HN)      // 8192
#define BH (HB*HH)        // 96

using s16x4  = __attribute__((ext_vector_type(4))) short;
using bf16x8 = __attribute__((ext_vector_type(8))) short;
using f32x4  = __attribute__((ext_vector_type(4))) float;

__device__ __forceinline__ short f2bf(float f) {
  union { float f; uint32_t u; } c; c.f = f;
  uint32_t u = c.u;
  uint32_t r = (u + 0x7fffu + ((u >> 16) & 1u)) >> 16;   // RNE
  return (short)r;
}
__device__ __forceinline__ float bf2f(short s) {
  union { uint32_t u; float f; } c; c.u = ((uint32_t)(uint16_t)s) << 16;
  return c.f;
}
// pack two f32 -> {bf16(a) | bf16(b)<<16} with RNE, via v_perm_b32
__device__ __forceinline__ uint32_t pack_bf16_rne(float a, float b) {
  union { float f; uint32_t u; } ca, cb; ca.f = a; cb.f = b;
  uint32_t ra = ca.u + 0x7fffu + ((ca.u >> 16) & 1u);
  uint32_t rb = cb.u + 0x7fffu + ((cb.u >> 16) & 1u);
  return __builtin_amdgcn_perm(rb, ra, 0x07060302);  // {rb[31:16], ra[31:16]}
}
__device__ __forceinline__ float fast_exp2(float x) {
#if __has_builtin(__builtin_amdgcn_exp2f)
  return __builtin_amdgcn_exp2f(x);
#else
  return exp2f(x);
#endif
}
__device__ __forceinline__ f32x4 mfma16(bf16x8 a, bf16x8 b, f32x4 c) {
  return __builtin_amdgcn_mfma_f32_16x16x32_bf16(a, b, c, 0, 0, 0);
}
// async global->LDS, 16B per lane. LDS dest MUST be wave-uniform base + lane*16.
__device__ __forceinline__ void gll16(const void* g, void* l) {
  __builtin_amdgcn_global_load_lds((const __attribute__((address_space(1))) void*)g,
                                   (__attribute__((address_space(3))) void*)l,
                                   16, 0, 0);
}

// ---------------- f32 -> bf16 convert (vectorized x4) ----------------
__global__ void cvt_kernel(const float* __restrict__ in, short* __restrict__ out, int n4) {
  int i = blockIdx.x * 256 + threadIdx.x;
  if (i >= n4) return;
  float4 v = ((const float4*)in)[i];
  s16x4 o;
  o.x = f2bf(v.x); o.y = f2bf(v.y); o.z = f2bf(v.z); o.w = f2bf(v.w);
  ((s16x4*)out)[i] = o;
}

// ---------------- GEMM: C[M,N] = A[M,K] * B[N,K]^T  (bf16 in, OutT out) ------
// m97 recipe: 128x128 tile, BK=64, 256 threads = 4 waves (2x2), each wave 64x64
// = 4x4 tiles of 16x16x32 MFMA. global_load_lds width 16 staging.
__device__ __forceinline__ void store_c(float* p, float v) { *p = v; }
__device__ __forceinline__ void store_c(short* p, float v) { *p = f2bf(v); }

template <typename OutT>
__global__ __launch_bounds__(256) void gemm_bt(const short* __restrict__ A,
                                               const short* __restrict__ Bw,
                                               OutT* __restrict__ C,
                                               int M, int N, int K) {
  __shared__ short As[128*64];
  __shared__ short Bs[128*64];
  const int m0 = blockIdx.y * 128, n0 = blockIdx.x * 128;
  const int tid = threadIdx.x;
  const int lane = tid & 63, w = tid >> 6, quad = lane >> 4, lc = lane & 15;
  const int wr = w >> 1, wc = w & 1;
  f32x4 acc[4][4] = {};
  for (int kt = 0; kt < K; kt += 64) {
#pragma unroll
    for (int i = 0; i < 4; ++i) {
      const int chunk = i*256 + tid;          // 1024 chunks of 8 elems = 128x64
      const int r = chunk >> 3, cb = chunk & 7;
      gll16(A  + (size_t)(m0 + r)*K + kt + cb*8, (void*)(As + (size_t)chunk*8));
      gll16(Bw + (size_t)(n0 + r)*K + kt + cb*8, (void*)(Bs + (size_t)chunk*8));
    }
    __syncthreads();
#pragma unroll
    for (int kk = 0; kk < 2; ++kk) {
      bf16x8 af[4], bfr[4];
#pragma unroll
      for (int mt = 0; mt < 4; ++mt)
        af[mt] = *(const bf16x8*)(As + (wr*64 + mt*16 + lc)*64 + kk*32 + quad*8);
#pragma unroll
      for (int nt = 0; nt < 4; ++nt)
        bfr[nt] = *(const bf16x8*)(Bs + (wc*64 + nt*16 + lc)*64 + kk*32 + quad*8);
#pragma unroll
      for (int mt = 0; mt < 4; ++mt)
#pragma unroll
        for (int nt = 0; nt < 4; ++nt)
          acc[mt][nt] = mfma16(af[mt], bfr[nt], acc[mt][nt]);
    }
    __syncthreads();
  }
  // epilogue: C/D layout col=lane&15, row=quad*4+reg  (m89/m91 verified)
#pragma unroll
  for (int mt = 0; mt < 4; ++mt)
#pragma unroll
    for (int nt = 0; nt < 4; ++nt)
#pragma unroll
      for (int r = 0; r < 4; ++r) {
        const int row = m0 + wr*64 + mt*16 + quad*4 + r;
        const int col = n0 + wc*64 + nt*16 + lc;
        store_c(C + (size_t)row*N + col, acc[mt][nt][r]);
      }
}

// ---------------- per-head LayerNorm(q,k) + V transpose/permute --------------
// qkvb: bf16 [8192][2304], col = t*768 + h*64 + d
// Qb,Kb: bf16 [BH][1024][64]   (q scaled by 1/8)
// Vtb  : bf16 [BH][64][1024]   transposed AND key-permuted per 128-chunk:
//   storage col c (within chunk) holds key k = (c&7)*16 + (c>>3)
//   (equivalently c = (k&15)*8 + (k>>4)) — matches the b128 P stash in attn.
// 128-row tiles so the permuted writes stay contiguous b128.
__global__ __launch_bounds__(256) void ln_qkv_kernel(const short* __restrict__ qkvb,
                                                     short* __restrict__ Qb,
                                                     short* __restrict__ Kb,
                                                     short* __restrict__ Vtb) {
  const int blk = blockIdx.x;            // bh*8 + tile
  const int tile = blk & 7, bh = blk >> 3;
  const int b = bh / HH, h = bh % HH;
  const int n0 = tile * 128;
  const int tid = threadIdx.x, w = tid >> 6, lane = tid & 63;

  // q (t=0, scaled) and k (t=1): one row per wave pass, lane=d
#pragma unroll
  for (int t = 0; t < 2; ++t) {
    const int colbase = t*HC + h*HD;
    short* outp = (t == 0) ? Qb : Kb;
    for (int i = 0; i < 32; ++i) {
      const int n = n0 + w*32 + i;
      const float v = bf2f(qkvb[(size_t)(b*HN + n)*(3*HC) + colbase + lane]);
      float s = v;
#pragma unroll
      for (int off = 1; off < 64; off <<= 1) s += __shfl_xor(s, off);
      const float mean = s * (1.0f/64.0f);
      const float d = v - mean;
      float s2 = d*d;
#pragma unroll
      for (int off = 1; off < 64; off <<= 1) s2 += __shfl_xor(s2, off);
      const float inv = rsqrtf(s2 * (1.0f/64.0f) + 1e-5f);
      float o = d * inv;
      if (t == 0) o *= 0.125f;           // SCALE = 64^-0.5
      outp[((size_t)bh*HN + n)*HD + lane] = f2bf(o);
    }
  }
  // v: 128x64 tile -> transpose + key-permute, b128 coalesced writes
  __shared__ float vt[128][65];
#pragma unroll
  for (int i = 0; i < 32; ++i) {
    const int idx = i*256 + tid; const int r = idx >> 6, dcol = idx & 63;
    vt[r][dcol] = bf2f(qkvb[(size_t)(b*HN + n0 + r)*(3*HC) + 2*HC + h*HD + dcol]);
  }
  __syncthreads();
#pragma unroll
  for (int it = 0; it < 4; ++it) {
    const int idx = it*256 + tid;
    const int dd = idx >> 4, j = idx & 15;   // dd in [0,64), j in [0,16)
    bf16x8 o;
#pragma unroll
    for (int t3 = 0; t3 < 8; ++t3)           // storage col c = j*8+t3 <-> key t3*16+j
      o[t3] = f2bf(vt[t3*16 + j][dd]);
    *(bf16x8*)(Vtb + ((size_t)bh*HD + dd)*HN + n0 + j*8) = o;
  }
}

// ---------------- flash attention (pipelined staging, fixed-max softmax) -----
// 1 block per (bh, 64-row q-tile). 4 waves x 16 q-rows. K/V chunks of 128.
// Register-prefetch pipeline: next chunk's K/V global loads issue at the top of
// compute (full compute-phase head start before the barrier's vmcnt drain);
// ds_write into padded LDS after the barrier -> both barriers are cheap.
// Fixed-max softmax: LN guarantees |q̂|=1, |k̂|=8 => S in [-8,8]; exp(S-8) is
// exactly shift-invariant softmax -> no max reduce, no rescaling; l-sum
// reduced across lanes only in the epilogue.
__global__ __launch_bounds__(256, 3) void attn_kernel(const short* __restrict__ Qb,
                                                      const short* __restrict__ Kb,
                                                      const short* __restrict__ Vtb,
                                                      short* __restrict__ AOb) {
  const int blk = blockIdx.x;
  const int qt = blk & 15, bh = blk >> 4;
  const int b = bh / HH, h = bh % HH;
  const int tid = threadIdx.x, w = tid >> 6, lane = tid & 63;
  const int quad = lane >> 4, lc = lane & 15;

  __shared__ short Ks [128][72];     // K chunk, padded (write/read bank-optimal)
  __shared__ short Vts[64][136];     // Vt chunk (key-permuted storage)
  __shared__ short Ps [4][16][136];  // per-wave P stash (b128 write/read)

  // Q A-fragments: A[m=lane&15][k=quad*8+j] (m120-verified layout)
  const int mrow = qt*64 + w*16 + lc;
  bf16x8 aq[2];
  aq[0] = *(const bf16x8*)(Qb + ((size_t)bh*HN + mrow)*HD + quad*8);
  aq[1] = *(const bf16x8*)(Qb + ((size_t)bh*HN + mrow)*HD + 32 + quad*8);

  const short* kbh = Kb  + (size_t)bh*HN*HD;
  const short* vbh = Vtb + (size_t)bh*HD*HN;

  f32x4 oacc[4] = {};
  float l_i[4] = {0.f, 0.f, 0.f, 0.f};

  // staging registers (chunk = i*256+tid; K: r=c>>3,cb=c&7; V: dd=c>>4,cb=c&15)
  bf16x8 gk[4], gv[4];
#pragma unroll
  for (int i = 0; i < 4; ++i) {
    const int c = i*256 + tid;
    gk[i] = *(const bf16x8*)(kbh + (size_t)(c >> 3)*HD + (c & 7)*8);
    gv[i] = *(const bf16x8*)(vbh + (size_t)(c >> 4)*HN + (c & 15)*8);
  }
#pragma unroll
  for (int i = 0; i < 4; ++i) {
    const int c = i*256 + tid;
    *(bf16x8*)(&Ks [c >> 3][(c & 7)*8])  = gk[i];
    *(bf16x8*)(&Vts[c >> 4][(c & 15)*8]) = gv[i];
  }
  __syncthreads();

  const float LOG2E = 1.44269504f;
  const float MB2   = 8.0f * 1.44269504f;   // fixed max * log2(e)

  for (int ck = 0; ck < 8; ++ck) {
    // prefetch chunk ck+1 into registers (overlaps with compute below)
    if (ck < 7) {
      const int nn0 = (ck + 1)*128;
#pragma unroll
      for (int i = 0; i < 4; ++i) {
        const int c = i*256 + tid;
        gk[i] = *(const bf16x8*)(kbh + (size_t)(nn0 + (c >> 3))*HD + (c & 7)*8);
        gv[i] = *(const bf16x8*)(vbh + (size_t)(c >> 4)*HN + nn0 + (c & 15)*8);
      }
    }

    // S = Q K^T : 16 MFMAs; sacc[nt] covers key cols nt*16+lc, rows quad*4+r
    f32x4 sacc[8] = {};
#pragma unroll
    for (int kk = 0; kk < 2; ++kk)
#pragma unroll
      for (int nt = 0; nt < 8; ++nt) {
        bf16x8 bk = *(const bf16x8*)(&Ks[nt*16 + lc][kk*32 + quad*8]);
        sacc[nt] = mfma16(aq[kk], bk, sacc[nt]);
      }

    // fixed-max softmax: p = exp2(S*log2e - 8*log2e); accumulate per-lane l
#pragma unroll
    for (int r = 0; r < 4; ++r) {
      float ps[8];
#pragma unroll
      for (int nt = 0; nt < 8; ++nt) {
        ps[nt] = fast_exp2(__builtin_fmaf(sacc[nt][r], LOG2E, -MB2));
        sacc[nt][r] = ps[nt];
      }
      l_i[r] += ((ps[0]+ps[1]) + (ps[2]+ps[3])) + ((ps[4]+ps[5]) + (ps[6]+ps[7]));
    }

    // P stash: C-layout -> A-layout, one b128 per row r.
    // storage col c = lc*8 + nt <-> original key nt*16+lc (matches Vtb perm)
#pragma unroll
    for (int r = 0; r < 4; ++r) {
      uint32_t pk0 = pack_bf16_rne(sacc[0][r], sacc[1][r]);
      uint32_t pk1 = pack_bf16_rne(sacc[2][r], sacc[3][r]);
      uint32_t pk2 = pack_bf16_rne(sacc[4][r], sacc[5][r]);
      uint32_t pk3 = pack_bf16_rne(sacc[6][r], sacc[7][r]);
      uint4 pk = make_uint4(pk0, pk1, pk2, pk3);
      *(uint4*)(&Ps[w][quad*4 + r][lc*8]) = pk;
    }

    // O += P V : 16 MFMAs (A from Ps, B from Vts; both in permuted key space)
#pragma unroll
    for (int kk = 0; kk < 4; ++kk) {
      bf16x8 ap = *(const bf16x8*)(&Ps[w][lc][kk*32 + quad*8]);
#pragma unroll
      for (int nt2 = 0; nt2 < 4; ++nt2) {
        bf16x8 bv = *(const bf16x8*)(&Vts[nt2*16 + lc][kk*32 + quad*8]);
        oacc[nt2] = mfma16(ap, bv, oacc[nt2]);
      }
    }

    __syncthreads();   // all waves done reading Ks/Vts (drains prefetch vmcnt too)
    if (ck < 7) {
#pragma unroll
      for (int i = 0; i < 4; ++i) {
        const int c = i*256 + tid;
        *(bf16x8*)(&Ks [c >> 3][(c & 7)*8])  = gk[i];
        *(bf16x8*)(&Vts[c >> 4][(c & 15)*8]) = gv[i];
      }
      __syncthreads();
    }
  }

  // epilogue: reduce l across the 16 lanes of each quad, then scale & store
  float rl[4];
#pragma unroll
  for (int r = 0; r < 4; ++r) {
    float l = l_i[r];
#pragma unroll
    for (int off = 1; off < 16; off <<= 1) l += __shfl_xor(l, off);
    rl[r] = 1.0f / l;
  }
#pragma unroll
  for (int nt2 = 0; nt2 < 4; ++nt2)
#pragma unroll
    for (int r = 0; r < 4; ++r) {
      const int row = qt*64 + w*16 + quad*4 + r;
      const int d   = nt2*16 + lc;
      AOb[((size_t)(b*HN + row))*HC + h*HD + d] = f2bf(oacc[nt2][r] * rl[r]);
    }
}

// ---------------- launch ----------------
extern "C" void kernel_launch(void* const* d_in, const int* in_sizes, int n_in,
                              void* d_out, int out_size, void* d_ws, size_t ws_size,
                              hipStream_t stream) {
  const float* x     = (const float*)d_in[0];
  const float* wqkv  = (const float*)d_in[1];
  const float* wproj = (const float*)d_in[2];
  float* out = (float*)d_out;

  char* ws = (char*)d_ws;
  size_t off = 0;
  auto alloc = [&](size_t bytes) -> void* {
    void* p = ws + off; off += (bytes + 255) & ~(size_t)255; return p;
  };
  short* xb     = (short*)alloc((size_t)ROWS*HC*2);        // 12.6 MB
  short* wqkvb  = (short*)alloc((size_t)3*HC*HC*2);        //  3.5 MB
  short* wprojb = (short*)alloc((size_t)HC*HC*2);          //  1.2 MB
  short* qkvb   = (short*)alloc((size_t)ROWS*3*HC*2);      // 37.7 MB
  short* Qb     = (short*)alloc((size_t)BH*HN*HD*2);       // 12.6 MB
  short* Kb     = (short*)alloc((size_t)BH*HN*HD*2);       // 12.6 MB
  short* Vtb    = (short*)alloc((size_t)BH*HD*HN*2);       // 12.6 MB
  short* AOb    = (short*)alloc((size_t)ROWS*HC*2);        // 12.6 MB  (~105 MB total)

  { int n4 = ROWS*HC/4;     cvt_kernel<<<(n4+255)/256, 256, 0, stream>>>(x, xb, n4); }
  { int n4 = 3*HC*HC/4;     cvt_kernel<<<(n4+255)/256, 256, 0, stream>>>(wqkv, wqkvb, n4); }
  { int n4 = HC*HC/4;       cvt_kernel<<<(n4+255)/256, 256, 0, stream>>>(wproj, wprojb, n4); }

  gemm_bt<short><<<dim3(3*HC/128, ROWS/128), 256, 0, stream>>>(xb, wqkvb, qkvb,
                                                               ROWS, 3*HC, HC);
  ln_qkv_kernel<<<BH*8, 256, 0, stream>>>(qkvb, Qb, Kb, Vtb);
  attn_kernel<<<BH*16, 256, 0, stream>>>(Qb, Kb, Vtb, AOb);
  gemm_bt<float><<<dim3(HC/128, ROWS/128), 256, 0, stream>>>(AOb, wprojb, out,
                                                             ROWS, HC, HC);
}

// Round 4
// 244.936 us; speedup vs baseline: 1.5565x; 1.0823x over previous
//
#include <hip/hip_runtime.h>
#include <stdint.h>
#include <stddef.h>

// Problem constants
#define HB 8
#define HN 1024
#define HC 768
#define HH 12
#define HD 64
#define ROWS (HB*HN)      // 8192
#define BH (HB*HH)        // 96

using s16x4  = __attribute__((ext_vector_type(4))) short;
using bf16x8 = __attribute__((ext_vector_type(8))) short;
using f32x4  = __attribute__((ext_vector_type(4))) float;

__device__ __forceinline__ short f2bf(float f) {
  union { float f; uint32_t u; } c; c.f = f;
  uint32_t u = c.u;
  uint32_t r = (u + 0x7fffu + ((u >> 16) & 1u)) >> 16;   // RNE
  return (short)r;
}
__device__ __forceinline__ float bf2f(short s) {
  union { uint32_t u; float f; } c; c.u = ((uint32_t)(uint16_t)s) << 16;
  return c.f;
}
// pack two f32 -> {bf16(a) | bf16(b)<<16} with RNE, via v_perm_b32
__device__ __forceinline__ uint32_t pack_bf16_rne(float a, float b) {
  union { float f; uint32_t u; } ca, cb; ca.f = a; cb.f = b;
  uint32_t ra = ca.u + 0x7fffu + ((ca.u >> 16) & 1u);
  uint32_t rb = cb.u + 0x7fffu + ((cb.u >> 16) & 1u);
  return __builtin_amdgcn_perm(rb, ra, 0x07060302);  // {rb[31:16], ra[31:16]}
}
__device__ __forceinline__ float fast_exp2(float x) {
#if __has_builtin(__builtin_amdgcn_exp2f)
  return __builtin_amdgcn_exp2f(x);
#else
  return exp2f(x);
#endif
}
__device__ __forceinline__ f32x4 mfma16(bf16x8 a, bf16x8 b, f32x4 c) {
  return __builtin_amdgcn_mfma_f32_16x16x32_bf16(a, b, c, 0, 0, 0);
}
// async global->LDS, 16B per lane. LDS dest MUST be wave-uniform base + lane*16.
__device__ __forceinline__ void gll16(const void* g, void* l) {
  __builtin_amdgcn_global_load_lds((const __attribute__((address_space(1))) void*)g,
                                   (__attribute__((address_space(3))) void*)l,
                                   16, 0, 0);
}

// ---------------- fused f32 -> bf16 convert for all 3 inputs ----------------
__global__ void cvt3_kernel(const float* __restrict__ x,  short* __restrict__ xb,  int n0,
                            const float* __restrict__ wq, short* __restrict__ wqb, int n1,
                            const float* __restrict__ wp, short* __restrict__ wpb, int n2) {
  int i = blockIdx.x * 256 + threadIdx.x;        // index in float4 units
  const float* in; short* out;
  if (i < n0)            { in = x;  out = xb;  }
  else if (i < n0 + n1)  { i -= n0; in = wq; out = wqb; }
  else if (i < n0 + n1 + n2) { i -= n0 + n1; in = wp; out = wpb; }
  else return;
  float4 v = ((const float4*)in)[i];
  s16x4 o;
  o.x = f2bf(v.x); o.y = f2bf(v.y); o.z = f2bf(v.z); o.w = f2bf(v.w);
  ((s16x4*)out)[i] = o;
}

// ---------------- GEMM: C[M,N] = A[M,K] * B[N,K]^T  (bf16 in, OutT out) ------
// m97 recipe: 128x128 tile, BK=64, 256 threads = 4 waves (2x2), each wave 64x64
// = 4x4 tiles of 16x16x32 MFMA. global_load_lds width 16 staging.
// XOR-swizzled LDS layout (R4): LDS chunk (r, cb) holds global k-chunk
// cb^(r&7); fragment reads de-swizzle with kb^(lc&7). This spreads a quad's
// 16 lanes over 8 distinct 4-bank groups (2-way = free) instead of all 16
// hitting one group (16-way conflict, the 1.06e7 SQ_LDS_BANK_CONFLICT in R3).
// Source-side permute keeps global coalescing (16-B pieces within one row).
__device__ __forceinline__ void store_c(float* p, float v) { *p = v; }
__device__ __forceinline__ void store_c(short* p, float v) { *p = f2bf(v); }

template <typename OutT>
__global__ __launch_bounds__(256) void gemm_bt(const short* __restrict__ A,
                                               const short* __restrict__ Bw,
                                               OutT* __restrict__ C,
                                               int M, int N, int K) {
  __shared__ short As[128*64];
  __shared__ short Bs[128*64];
  const int m0 = blockIdx.y * 128, n0 = blockIdx.x * 128;
  const int tid = threadIdx.x;
  const int lane = tid & 63, w = tid >> 6, quad = lane >> 4, lc = lane & 15;
  const int wr = w >> 1, wc = w & 1;
  f32x4 acc[4][4] = {};
  for (int kt = 0; kt < K; kt += 64) {
#pragma unroll
    for (int i = 0; i < 4; ++i) {
      const int chunk = i*256 + tid;          // 1024 chunks of 8 elems = 128x64
      const int r = chunk >> 3, cb = chunk & 7;
      const int cbs = cb ^ (r & 7);           // source k-chunk (swizzle)
      gll16(A  + (size_t)(m0 + r)*K + kt + cbs*8, (void*)(As + (size_t)chunk*8));
      gll16(Bw + (size_t)(n0 + r)*K + kt + cbs*8, (void*)(Bs + (size_t)chunk*8));
    }
    __syncthreads();
#pragma unroll
    for (int kk = 0; kk < 2; ++kk) {
      bf16x8 af[4], bfr[4];
#pragma unroll
      for (int mt = 0; mt < 4; ++mt) {
        const int kb = kk*4 + quad;
        af[mt] = *(const bf16x8*)(As + (wr*64 + mt*16 + lc)*64 + (kb ^ (lc & 7))*8);
      }
#pragma unroll
      for (int nt = 0; nt < 4; ++nt) {
        const int kb = kk*4 + quad;
        bfr[nt] = *(const bf16x8*)(Bs + (wc*64 + nt*16 + lc)*64 + (kb ^ (lc & 7))*8);
      }
#pragma unroll
      for (int mt = 0; mt < 4; ++mt)
#pragma unroll
        for (int nt = 0; nt < 4; ++nt)
          acc[mt][nt] = mfma16(af[mt], bfr[nt], acc[mt][nt]);
    }
    __syncthreads();
  }
  // epilogue: C/D layout col=lane&15, row=quad*4+reg  (m89/m91 verified)
#pragma unroll
  for (int mt = 0; mt < 4; ++mt)
#pragma unroll
    for (int nt = 0; nt < 4; ++nt)
#pragma unroll
      for (int r = 0; r < 4; ++r) {
        const int row = m0 + wr*64 + mt*16 + quad*4 + r;
        const int col = n0 + wc*64 + nt*16 + lc;
        store_c(C + (size_t)row*N + col, acc[mt][nt][r]);
      }
}

// ---------------- per-head LayerNorm(q,k) + V transpose/permute --------------
// qkvb: bf16 [8192][2304], col = t*768 + h*64 + d
// Qb,Kb: bf16 [BH][1024][64]   (q scaled by 1/8)
// Vtb  : bf16 [BH][64][1024]   transposed AND key-permuted per 128-chunk:
//   storage col c (within chunk) holds key k = (c&7)*16 + (c>>3)
//   (equivalently c = (k&15)*8 + (k>>4)) — matches the b128 P stash in attn.
// 128-row tiles so the permuted writes stay contiguous b128.
__global__ __launch_bounds__(256) void ln_qkv_kernel(const short* __restrict__ qkvb,
                                                     short* __restrict__ Qb,
                                                     short* __restrict__ Kb,
                                                     short* __restrict__ Vtb) {
  const int blk = blockIdx.x;            // bh*8 + tile
  const int tile = blk & 7, bh = blk >> 3;
  const int b = bh / HH, h = bh % HH;
  const int n0 = tile * 128;
  const int tid = threadIdx.x, w = tid >> 6, lane = tid & 63;

  // q (t=0, scaled) and k (t=1): one row per wave pass, lane=d
#pragma unroll
  for (int t = 0; t < 2; ++t) {
    const int colbase = t*HC + h*HD;
    short* outp = (t == 0) ? Qb : Kb;
    for (int i = 0; i < 32; ++i) {
      const int n = n0 + w*32 + i;
      const float v = bf2f(qkvb[(size_t)(b*HN + n)*(3*HC) + colbase + lane]);
      float s = v;
#pragma unroll
      for (int off = 1; off < 64; off <<= 1) s += __shfl_xor(s, off);
      const float mean = s * (1.0f/64.0f);
      const float d = v - mean;
      float s2 = d*d;
#pragma unroll
      for (int off = 1; off < 64; off <<= 1) s2 += __shfl_xor(s2, off);
      const float inv = rsqrtf(s2 * (1.0f/64.0f) + 1e-5f);
      float o = d * inv;
      if (t == 0) o *= 0.125f;           // SCALE = 64^-0.5
      outp[((size_t)bh*HN + n)*HD + lane] = f2bf(o);
    }
  }
  // v: 128x64 tile -> transpose + key-permute, b128 coalesced writes
  __shared__ float vt[128][65];
#pragma unroll
  for (int i = 0; i < 32; ++i) {
    const int idx = i*256 + tid; const int r = idx >> 6, dcol = idx & 63;
    vt[r][dcol] = bf2f(qkvb[(size_t)(b*HN + n0 + r)*(3*HC) + 2*HC + h*HD + dcol]);
  }
  __syncthreads();
#pragma unroll
  for (int it = 0; it < 4; ++it) {
    const int idx = it*256 + tid;
    const int dd = idx >> 4, j = idx & 15;   // dd in [0,64), j in [0,16)
    bf16x8 o;
#pragma unroll
    for (int t3 = 0; t3 < 8; ++t3)           // storage col c = j*8+t3 <-> key t3*16+j
      o[t3] = f2bf(vt[t3*16 + j][dd]);
    *(bf16x8*)(Vtb + ((size_t)bh*HD + dd)*HN + n0 + j*8) = o;
  }
}

// ---------------- flash attention (pipelined staging, fixed-max softmax) -----
// 1 block per (bh, 64-row q-tile). 4 waves x 16 q-rows. K/V chunks of 128.
// Register-prefetch pipeline: next chunk's K/V global loads issue at the top of
// compute (full compute-phase head start before the barrier's vmcnt drain);
// ds_write into padded LDS after the barrier -> both barriers are cheap.
// Fixed-max softmax: LN guarantees |q̂|=1, |k̂|=8 => S in [-8,8]; exp(S-8) is
// exactly shift-invariant softmax -> no max reduce, no rescaling; l-sum
// reduced across lanes only in the epilogue.
__global__ __launch_bounds__(256, 3) void attn_kernel(const short* __restrict__ Qb,
                                                      const short* __restrict__ Kb,
                                                      const short* __restrict__ Vtb,
                                                      short* __restrict__ AOb) {
  const int blk = blockIdx.x;
  const int qt = blk & 15, bh = blk >> 4;
  const int b = bh / HH, h = bh % HH;
  const int tid = threadIdx.x, w = tid >> 6, lane = tid & 63;
  const int quad = lane >> 4, lc = lane & 15;

  __shared__ short Ks [128][72];     // K chunk, padded (write/read bank-optimal)
  __shared__ short Vts[64][136];     // Vt chunk (key-permuted storage)
  __shared__ short Ps [4][16][136];  // per-wave P stash (b128 write/read)

  // Q A-fragments: A[m=lane&15][k=quad*8+j] (m120-verified layout)
  const int mrow = qt*64 + w*16 + lc;
  bf16x8 aq[2];
  aq[0] = *(const bf16x8*)(Qb + ((size_t)bh*HN + mrow)*HD + quad*8);
  aq[1] = *(const bf16x8*)(Qb + ((size_t)bh*HN + mrow)*HD + 32 + quad*8);

  const short* kbh = Kb  + (size_t)bh*HN*HD;
  const short* vbh = Vtb + (size_t)bh*HD*HN;

  f32x4 oacc[4] = {};
  float l_i[4] = {0.f, 0.f, 0.f, 0.f};

  // staging registers (chunk = i*256+tid; K: r=c>>3,cb=c&7; V: dd=c>>4,cb=c&15)
  bf16x8 gk[4], gv[4];
#pragma unroll
  for (int i = 0; i < 4; ++i) {
    const int c = i*256 + tid;
    gk[i] = *(const bf16x8*)(kbh + (size_t)(c >> 3)*HD + (c & 7)*8);
    gv[i] = *(const bf16x8*)(vbh + (size_t)(c >> 4)*HN + (c & 15)*8);
  }
#pragma unroll
  for (int i = 0; i < 4; ++i) {
    const int c = i*256 + tid;
    *(bf16x8*)(&Ks [c >> 3][(c & 7)*8])  = gk[i];
    *(bf16x8*)(&Vts[c >> 4][(c & 15)*8]) = gv[i];
  }
  __syncthreads();

  const float LOG2E = 1.44269504f;
  const float MB2   = 8.0f * 1.44269504f;   // fixed max * log2(e)

  for (int ck = 0; ck < 8; ++ck) {
    // prefetch chunk ck+1 into registers (overlaps with compute below)
    if (ck < 7) {
      const int nn0 = (ck + 1)*128;
#pragma unroll
      for (int i = 0; i < 4; ++i) {
        const int c = i*256 + tid;
        gk[i] = *(const bf16x8*)(kbh + (size_t)(nn0 + (c >> 3))*HD + (c & 7)*8);
        gv[i] = *(const bf16x8*)(vbh + (size_t)(c >> 4)*HN + nn0 + (c & 15)*8);
      }
    }

    // S = Q K^T : 16 MFMAs; sacc[nt] covers key cols nt*16+lc, rows quad*4+r
    f32x4 sacc[8] = {};
#pragma unroll
    for (int kk = 0; kk < 2; ++kk)
#pragma unroll
      for (int nt = 0; nt < 8; ++nt) {
        bf16x8 bk = *(const bf16x8*)(&Ks[nt*16 + lc][kk*32 + quad*8]);
        sacc[nt] = mfma16(aq[kk], bk, sacc[nt]);
      }

    // fixed-max softmax: p = exp2(S*log2e - 8*log2e); accumulate per-lane l
#pragma unroll
    for (int r = 0; r < 4; ++r) {
      float ps[8];
#pragma unroll
      for (int nt = 0; nt < 8; ++nt) {
        ps[nt] = fast_exp2(__builtin_fmaf(sacc[nt][r], LOG2E, -MB2));
        sacc[nt][r] = ps[nt];
      }
      l_i[r] += ((ps[0]+ps[1]) + (ps[2]+ps[3])) + ((ps[4]+ps[5]) + (ps[6]+ps[7]));
    }

    // P stash: C-layout -> A-layout, one b128 per row r.
    // storage col c = lc*8 + nt <-> original key nt*16+lc (matches Vtb perm)
#pragma unroll
    for (int r = 0; r < 4; ++r) {
      uint32_t pk0 = pack_bf16_rne(sacc[0][r], sacc[1][r]);
      uint32_t pk1 = pack_bf16_rne(sacc[2][r], sacc[3][r]);
      uint32_t pk2 = pack_bf16_rne(sacc[4][r], sacc[5][r]);
      uint32_t pk3 = pack_bf16_rne(sacc[6][r], sacc[7][r]);
      uint4 pk = make_uint4(pk0, pk1, pk2, pk3);
      *(uint4*)(&Ps[w][quad*4 + r][lc*8]) = pk;
    }

    // O += P V : 16 MFMAs (A from Ps, B from Vts; both in permuted key space)
#pragma unroll
    for (int kk = 0; kk < 4; ++kk) {
      bf16x8 ap = *(const bf16x8*)(&Ps[w][lc][kk*32 + quad*8]);
#pragma unroll
      for (int nt2 = 0; nt2 < 4; ++nt2) {
        bf16x8 bv = *(const bf16x8*)(&Vts[nt2*16 + lc][kk*32 + quad*8]);
        oacc[nt2] = mfma16(ap, bv, oacc[nt2]);
      }
    }

    __syncthreads();   // all waves done reading Ks/Vts (drains prefetch vmcnt too)
    if (ck < 7) {
#pragma unroll
      for (int i = 0; i < 4; ++i) {
        const int c = i*256 + tid;
        *(bf16x8*)(&Ks [c >> 3][(c & 7)*8])  = gk[i];
        *(bf16x8*)(&Vts[c >> 4][(c & 15)*8]) = gv[i];
      }
      __syncthreads();
    }
  }

  // epilogue: reduce l across the 16 lanes of each quad, then scale & store
  float rl[4];
#pragma unroll
  for (int r = 0; r < 4; ++r) {
    float l = l_i[r];
#pragma unroll
    for (int off = 1; off < 16; off <<= 1) l += __shfl_xor(l, off);
    rl[r] = 1.0f / l;
  }
#pragma unroll
  for (int nt2 = 0; nt2 < 4; ++nt2)
#pragma unroll
    for (int r = 0; r < 4; ++r) {
      const int row = qt*64 + w*16 + quad*4 + r;
      const int d   = nt2*16 + lc;
      AOb[((size_t)(b*HN + row))*HC + h*HD + d] = f2bf(oacc[nt2][r] * rl[r]);
    }
}

// ---------------- launch ----------------
extern "C" void kernel_launch(void* const* d_in, const int* in_sizes, int n_in,
                              void* d_out, int out_size, void* d_ws, size_t ws_size,
                              hipStream_t stream) {
  const float* x     = (const float*)d_in[0];
  const float* wqkv  = (const float*)d_in[1];
  const float* wproj = (const float*)d_in[2];
  float* out = (float*)d_out;

  char* ws = (char*)d_ws;
  size_t off = 0;
  auto alloc = [&](size_t bytes) -> void* {
    void* p = ws + off; off += (bytes + 255) & ~(size_t)255; return p;
  };
  short* xb     = (short*)alloc((size_t)ROWS*HC*2);        // 12.6 MB
  short* wqkvb  = (short*)alloc((size_t)3*HC*HC*2);        //  3.5 MB
  short* wprojb = (short*)alloc((size_t)HC*HC*2);          //  1.2 MB
  short* qkvb   = (short*)alloc((size_t)ROWS*3*HC*2);      // 37.7 MB
  short* Qb     = (short*)alloc((size_t)BH*HN*HD*2);       // 12.6 MB
  short* Kb     = (short*)alloc((size_t)BH*HN*HD*2);       // 12.6 MB
  short* Vtb    = (short*)alloc((size_t)BH*HD*HN*2);       // 12.6 MB
  short* AOb    = (short*)alloc((size_t)ROWS*HC*2);        // 12.6 MB  (~105 MB total)

  { const int n0 = ROWS*HC/4, n1 = 3*HC*HC/4, n2 = HC*HC/4;
    const int tot = n0 + n1 + n2;
    cvt3_kernel<<<(tot + 255)/256, 256, 0, stream>>>(x, xb, n0, wqkv, wqkvb, n1,
                                                     wproj, wprojb, n2); }

  gemm_bt<short><<<dim3(3*HC/128, ROWS/128), 256, 0, stream>>>(xb, wqkvb, qkvb,
                                                               ROWS, 3*HC, HC);
  ln_qkv_kernel<<<BH*8, 256, 0, stream>>>(qkvb, Qb, Kb, Vtb);
  attn_kernel<<<BH*16, 256, 0, stream>>>(Qb, Kb, Vtb, AOb);
  gemm_bt<float><<<dim3(HC/128, ROWS/128), 256, 0, stream>>>(AOb, wprojb, out,
                                                             ROWS, HC, HC);
}